// Round 5
// baseline (121.683 us; speedup 1.0000x reference)
//
#include <hip/hip_runtime.h>

#define B_N 16
#define C_N 3
#define H_N 512
#define W_N 512
#define PLANES (B_N * C_N)            // 48
#define ROWS_PER_BLOCK 32
#define CHUNKS (H_N / ROWS_PER_BLOCK) // 16
#define NBLK (PLANES * CHUNKS)        // 768
#define STATS3 (W_N * 3)              // 1536
#define K2_BLOCKS (PLANES * 2)        // 96 (2 blocks per plane, 256 cols each)
#define SCALE (-1.0f / 8192.0f)       // -1/(B*H) == -1/(B*W), weights all 1
#define EPS_F 1e-12f

// K1: single streaming pass, reads x and ref exactly once.
// Round-5 rationale: r2 proved K1 is not occupancy-bound (48% occ, same
// 45 µs); r0/r4 structure runs ~36 µs latency-bound (VALUBusy 12%, reads at
// ~2.3 TB/s effective, 0 bank conflicts). The last in-loop serialization is
// the 18-op cross-lane butterfly (3 stats x 6 shfl_down = ds_bpermute +
// dependent add) per iteration. This version removes ALL cross-lane ops
// from the streaming loop: each lane stores its 3 per-row partials to LDS
// (fire-and-forget ds_write, no lgkm wait until the barrier) and the 64-lane
// row reduction happens once, after the loop. Loop shape otherwise identical
// to r4 (rolled, un-pragma'd, same loads/registers).
// LDS: 24 KB row-partials + 24 KB col-combine = 48 KB -> 3 blocks/CU,
// exactly the 768-block grid's residency.
__global__ __launch_bounds__(256) void spl_main_kernel(
    const float* __restrict__ x, const float* __restrict__ r,
    float* __restrict__ colpart, float* __restrict__ rowpart,
    unsigned int* __restrict__ counter) {
    if (blockIdx.x == 0 && threadIdx.x == 0)
        __hip_atomic_store(counter, 0u, __ATOMIC_RELAXED, __HIP_MEMORY_SCOPE_AGENT);

    const int p     = blockIdx.x / CHUNKS;
    const int chunk = blockIdx.x % CHUNKS;
    const int wave  = threadIdx.x >> 6;
    const int lane  = threadIdx.x & 63;

    const float* xp = x + (size_t)p * (H_N * W_N);
    const float* rp = r + (size_t)p * (H_N * W_N);

    float cxx[8] = {0, 0, 0, 0, 0, 0, 0, 0};
    float crr[8] = {0, 0, 0, 0, 0, 0, 0, 0};
    float cxr[8] = {0, 0, 0, 0, 0, 0, 0, 0};

    // per-row, per-lane partials: [row][lane][stat], stride-3 words per lane
    // -> 2 lanes/bank max on ds_write (free on CDNA4). 24 KiB.
    __shared__ float rowlds[ROWS_PER_BLOCK][64][3];

    const int r0 = chunk * ROWS_PER_BLOCK;
    for (int j = 0; j < ROWS_PER_BLOCK / 4; ++j) {
        const int rl  = wave + 4 * j;  // local row 0..31
        const int row = r0 + rl;
        const float4* xr4 = (const float4*)(xp + (size_t)row * W_N);
        const float4* rr4 = (const float4*)(rp + (size_t)row * W_N);
        const float4 xa = xr4[lane];
        const float4 xb = xr4[lane + 64];
        const float4 ra = rr4[lane];
        const float4 rb = rr4[lane + 64];

        cxx[0] += xa.x * xa.x; cxx[1] += xa.y * xa.y; cxx[2] += xa.z * xa.z; cxx[3] += xa.w * xa.w;
        cxx[4] += xb.x * xb.x; cxx[5] += xb.y * xb.y; cxx[6] += xb.z * xb.z; cxx[7] += xb.w * xb.w;
        crr[0] += ra.x * ra.x; crr[1] += ra.y * ra.y; crr[2] += ra.z * ra.z; crr[3] += ra.w * ra.w;
        crr[4] += rb.x * rb.x; crr[5] += rb.y * rb.y; crr[6] += rb.z * rb.z; crr[7] += rb.w * rb.w;
        cxr[0] += xa.x * ra.x; cxr[1] += xa.y * ra.y; cxr[2] += xa.z * ra.z; cxr[3] += xa.w * ra.w;
        cxr[4] += xb.x * rb.x; cxr[5] += xb.y * rb.y; cxr[6] += xb.z * rb.z; cxr[7] += xb.w * rb.w;

        const float sxx = xa.x * xa.x + xa.y * xa.y + xa.z * xa.z + xa.w * xa.w
                        + xb.x * xb.x + xb.y * xb.y + xb.z * xb.z + xb.w * xb.w;
        const float srr = ra.x * ra.x + ra.y * ra.y + ra.z * ra.z + ra.w * ra.w
                        + rb.x * rb.x + rb.y * rb.y + rb.z * rb.z + rb.w * rb.w;
        const float sxr = xa.x * ra.x + xa.y * ra.y + xa.z * ra.z + xa.w * ra.w
                        + xb.x * rb.x + xb.y * rb.y + xb.z * rb.z + xb.w * rb.w;
        rowlds[rl][lane][0] = sxx;
        rowlds[rl][lane][1] = srr;
        rowlds[rl][lane][2] = sxr;
    }

    // col partials to LDS (own slots, no sync needed before writes)
    __shared__ float smem[4][STATS3];  // 24 KiB
    #pragma unroll
    for (int k = 0; k < 4; ++k) {
        const int c0 = 4 * lane + k;
        const int c1 = c0 + 256;
        smem[wave][c0 * 3 + 0] = cxx[k];
        smem[wave][c0 * 3 + 1] = crr[k];
        smem[wave][c0 * 3 + 2] = cxr[k];
        smem[wave][c1 * 3 + 0] = cxx[4 + k];
        smem[wave][c1 * 3 + 1] = crr[4 + k];
        smem[wave][c1 * 3 + 2] = cxr[4 + k];
    }
    __syncthreads();

    // colpart: coalesced stores (identical to r4)
    float* cp = colpart + (size_t)blockIdx.x * STATS3;
    #pragma unroll
    for (int k = 0; k < 6; ++k) {
        const int e = threadIdx.x + 256 * k;
        cp[e] = smem[0][e] + smem[1][e] + smem[2][e] + smem[3][e];
    }

    // row reduction: 96 threads, each owns one (row, stat); staggered scan
    // over 64 lanes (bank = (l*3+stat)&31: conflict-free within a stat,
    // 2-way across stats = free).
    __shared__ float rowstat[ROWS_PER_BLOCK][3];
    if (threadIdx.x < 96) {
        const int rr = threadIdx.x & 31;
        const int st = threadIdx.x >> 5;
        float s = 0.0f;
        for (int i = 0; i < 64; ++i) {
            const int l = (i + threadIdx.x) & 63;
            s += rowlds[rr][l][st];
        }
        rowstat[rr][st] = s;
    }
    __syncthreads();

    if (threadIdx.x < 64) {
        float term = 0.0f;
        if (threadIdx.x < ROWS_PER_BLOCK) {
            const float sxx = rowstat[threadIdx.x][0];
            const float srr = rowstat[threadIdx.x][1];
            const float sxr = rowstat[threadIdx.x][2];
            term = sxr / (fmaxf(sqrtf(sxx), EPS_F) * fmaxf(sqrtf(srr), EPS_F));
        }
        #pragma unroll
        for (int m = 16; m > 0; m >>= 1) term += __shfl_down(term, m, 64);
        if (threadIdx.x == 0) rowpart[blockIdx.x] = term;
    }
}

// K2 (fused final): 96 blocks, 2 per plane (256 columns each). Reduces the
// 16 chunk partials, forms 256 column cosine terms, half 0 adds the 16 row
// partial sums, publishes planepart[b] device-scope; the LAST block folds
// the 96 partials and writes the output (saves the K3 launch).
__global__ __launch_bounds__(256) void spl_reduce_kernel(
    const float* __restrict__ colpart, const float* __restrict__ rowpart,
    float* __restrict__ planepart, unsigned int* __restrict__ counter,
    float* __restrict__ out) {
    const int p    = blockIdx.x >> 1;
    const int half = blockIdx.x & 1;

    float acc0 = 0.0f, acc1 = 0.0f, acc2 = 0.0f;
    const float* base = colpart + (size_t)p * CHUNKS * STATS3 + half * 768;
    #pragma unroll 4
    for (int c = 0; c < CHUNKS; ++c) {
        const float* bc = base + c * STATS3;
        acc0 += bc[threadIdx.x];
        acc1 += bc[threadIdx.x + 256];
        acc2 += bc[threadIdx.x + 512];
    }
    __shared__ float sums[768];
    sums[threadIdx.x]       = acc0;
    sums[threadIdx.x + 256] = acc1;
    sums[threadIdx.x + 512] = acc2;
    __syncthreads();

    // one column per thread; stride-3 -> max 2 lanes/bank, free on CDNA4.
    const float sxx = sums[3 * threadIdx.x + 0];
    const float srr = sums[3 * threadIdx.x + 1];
    const float sxr = sums[3 * threadIdx.x + 2];
    float term = sxr / (fmaxf(sqrtf(sxx), EPS_F) * fmaxf(sqrtf(srr), EPS_F));
    if (half == 0 && threadIdx.x < CHUNKS)
        term += rowpart[p * CHUNKS + threadIdx.x];

    #pragma unroll
    for (int m = 32; m > 0; m >>= 1) term += __shfl_down(term, m, 64);
    __shared__ float ws4[4];
    if ((threadIdx.x & 63) == 0) ws4[threadIdx.x >> 6] = term;
    __syncthreads();

    __shared__ bool last;
    if (threadIdx.x == 0) {
        const float total = ws4[0] + ws4[1] + ws4[2] + ws4[3];
        __hip_atomic_store(&planepart[blockIdx.x], total, __ATOMIC_RELEASE,
                           __HIP_MEMORY_SCOPE_AGENT);
        const unsigned int prev = __hip_atomic_fetch_add(
            counter, 1u, __ATOMIC_ACQ_REL, __HIP_MEMORY_SCOPE_AGENT);
        last = (prev == K2_BLOCKS - 1);
    }
    __syncthreads();

    if (last && threadIdx.x < 64) {
        const int t = threadIdx.x;
        float v = __hip_atomic_load(&planepart[t], __ATOMIC_ACQUIRE,
                                    __HIP_MEMORY_SCOPE_AGENT);
        if (t < K2_BLOCKS - 64)
            v += __hip_atomic_load(&planepart[t + 64], __ATOMIC_ACQUIRE,
                                   __HIP_MEMORY_SCOPE_AGENT);
        #pragma unroll
        for (int m = 32; m > 0; m >>= 1) v += __shfl_down(v, m, 64);
        if (t == 0) out[0] = SCALE * v;
    }
}

extern "C" void kernel_launch(void* const* d_in, const int* in_sizes, int n_in,
                              void* d_out, int out_size, void* d_ws, size_t ws_size,
                              hipStream_t stream) {
    const float* x   = (const float*)d_in[0];
    const float* ref = (const float*)d_in[1];
    float* out = (float*)d_out;

    float* colpart   = (float*)d_ws;                      // 768*1536 floats
    float* rowpart   = colpart + (size_t)NBLK * STATS3;   // 768 floats
    float* planepart = rowpart + NBLK;                    // 96 floats
    unsigned int* counter = (unsigned int*)(planepart + K2_BLOCKS);  // 1 uint

    spl_main_kernel<<<NBLK, 256, 0, stream>>>(x, ref, colpart, rowpart, counter);
    spl_reduce_kernel<<<K2_BLOCKS, 256, 0, stream>>>(colpart, rowpart, planepart,
                                                     counter, out);
}